// Round 13
// baseline (5853.936 us; speedup 1.0000x reference)
//
#include <hip/hip_runtime.h>
#include <hip/hip_bf16.h>

// ConvLSTM (2 layers) on MI355X. R13: fp16 pipeline (R11, verified 2202us)
// with gate0 restructured to a BARRIER-FREE K-loop:
//   M_b = 64 px (one image row). Stage all 3 halo rows x 160 ch (63.4 KB) in
//   ONE shot -> ONE __syncthreads -> 45 tap-chunks with no barriers.
//   Wave tile 16px x 128co: per tap 1 ds_read_b128 + 8 MFMA (acc 8x float4 =
//   32 AGPR; bcur/bnxt[8] = 64 VGPR explicit 1-ahead B prefetch; Wp0 1.47MB
//   fp16 is L2-resident per XCD).
// LDS layout [row][v=ch8-group][px] keeps DMA wave-uniform+lane*16 AND makes
// af reads sequential-equivalent (conflict-free).
// P (B,64,64,160) fp16: [x(1), h0(128), h1(12), pad(19)]. gate1 = R11 verbatim.

typedef __attribute__((ext_vector_type(8))) short short8;
typedef __attribute__((ext_vector_type(4))) float float4v;

#define CS 160
#define KTOT 1440         // 9*160
#define VPITCH 528        // shorts per v-slot  (66 px * 8)
#define RPITCH 10560      // shorts per halo row (20 v * 528)

__device__ __forceinline__ float sigf(float x) { return 1.f / (1.f + __expf(-x)); }
__device__ __forceinline__ short f2hs(float v) {
  _Float16 h = (_Float16)v;
  return *(short*)&h;
}
__device__ __forceinline__ float bs2f(short s) {
  __hip_bfloat16 h; *(short*)&h = s; return __bfloat162float(h);
}
__device__ __forceinline__ short f2bs(float v) {
  __hip_bfloat16 h = __float2bfloat16(v);
  return *(short*)&h;
}

// async 16B global->LDS; per-lane lds dst is uniform_base + lane*16
__device__ __forceinline__ void async_ld16(const short* g, short* l) {
  __builtin_amdgcn_global_load_lds(
      (const __attribute__((address_space(1))) unsigned int*)g,
      (__attribute__((address_space(3))) unsigned int*)l, 16, 0, 0);
}

// ---- dtype detect ----
__global__ void detect_dtype(const unsigned short* __restrict__ w0, int* __restrict__ flag) {
  int lane = threadIdx.x;
  int cnt = 0;
  for (int i = 0; i < 4; ++i) {
    unsigned short u = w0[2 * (lane + 64 * i)];
    int e = (u >> 7) & 0xFF;
    unsigned long long b = __ballot(e >= 0xC0);
    cnt += __popcll(b);
  }
  if (lane == 0) *flag = (cnt > 32) ? 1 : 0;   // 1 = fp32 inputs
}

__global__ void canon_x(const void* __restrict__ hist, short* __restrict__ Xc,
                        const int* __restrict__ flag) {
  int i = blockIdx.x * 256 + threadIdx.x;      // < 786432
  float v = (*flag) ? ((const float*)hist)[i] : bs2f(((const short*)hist)[i]);
  if (!isfinite(v) || fabsf(v) > 1e4f) v = 0.f;
  Xc[i] = f2hs(v);
}

__global__ void canon_b(const void* __restrict__ b0, const void* __restrict__ b1,
                        float* __restrict__ Bc0, float* __restrict__ Bc1,
                        const int* __restrict__ flag) {
  int i = blockIdx.x * 256 + threadIdx.x;
  int fl = *flag;
  if (i < 512) {
    float v = fl ? ((const float*)b0)[i] : bs2f(((const short*)b0)[i]);
    if (!isfinite(v) || fabsf(v) > 1e4f) v = 0.f;
    Bc0[i] = v;
  } else if (i < 560) {
    int j = i - 512;
    float v = fl ? ((const float*)b1)[j] : bs2f(((const short*)b1)[j]);
    if (!isfinite(v) || fabsf(v) > 1e4f) v = 0.f;
    Bc1[j] = v;
  }
}

// layer0 W0 (512,129,3,3) -> fp16 Wp[co][tap*160+c]: P-ch 0=x, 1..128=h0, else 0.
__global__ void prep_w0(const void* __restrict__ W0, short* __restrict__ Wp,
                        const int* __restrict__ flag) {
  int i = blockIdx.x * 256 + threadIdx.x;
  if (i >= 512 * KTOT) return;
  int fl = *flag;
  int co = i / KTOT, k = i - co * KTOT;
  int tap = k / CS, c = k - tap * CS;
  int ci = -1;
  if (c == 0) ci = 0;
  else if (c <= 128) ci = c;
  float w = 0.f;
  if (ci >= 0) {
    int widx = (co * 129 + ci) * 9 + tap;
    w = fl ? ((const float*)W0)[widx] : bs2f(((const short*)W0)[widx]);
    if (!isfinite(w) || fabsf(w) > 1e4f) w = 0.f;
  }
  Wp[i] = f2hs(w);
}

// layer1 W1 (48,140,3,3) -> fp16: P-ch 1..128=h0, 129..140=h1, else 0.
__global__ void prep_w1(const void* __restrict__ W1, short* __restrict__ Wp,
                        const int* __restrict__ flag) {
  int i = blockIdx.x * 256 + threadIdx.x;
  if (i >= 48 * KTOT) return;
  int fl = *flag;
  int co = i / KTOT, k = i - co * KTOT;
  int tap = k / CS, c = k - tap * CS;
  int ci = -1;
  if (c >= 1 && c <= 140) ci = c - 1;
  float w = 0.f;
  if (ci >= 0) {
    int widx = (co * 140 + ci) * 9 + tap;
    w = fl ? ((const float*)W1)[widx] : bs2f(((const short*)W1)[widx]);
    if (!isfinite(w) || fabsf(w) > 1e4f) w = 0.f;
  }
  Wp[i] = f2hs(w);
}

__global__ void fill_x0(const short* __restrict__ Xc, short* __restrict__ P0) {
  int p = blockIdx.x * 256 + threadIdx.x;      // b*4096 + pix
  int b = p >> 12, pix = p & 4095;
  P0[(size_t)p * CS] = Xc[b * 12 * 4096 + pix];
}

// ---- layer 0: M_b=64px (1 row) x N_b=128co. Grid 4096 = (b,y) x 4 nt (nt=bx&3).
// LDS: halo[r][v][px] r<3, v<20 (v = ch*4+quad, 8ch each), px<66.
// One stage + one barrier, then 45 tap-chunks barrier-free.
__global__ __launch_bounds__(256, 2) void gemm_gate0(
    const short* __restrict__ Pcur, short* __restrict__ Pnext,
    const short* __restrict__ Wp, const float* __restrict__ Bc0,
    float* __restrict__ C0, const short* __restrict__ Xc,
    const short* __restrict__ zp, int t) {
  int bx = blockIdx.x;
  int nt = bx & 3, mt = bx >> 2;               // nt siblings adjacent; mt y-major
  int y = mt & 63, b = mt >> 6;
  int tid = threadIdx.x, wave = tid >> 6, lane = tid & 63;
  int ln15 = lane & 15, quad = lane >> 4;

  __shared__ __align__(16) short halo[3 * RPITCH];   // 63360 B

  // ---- stage 3 halo rows x 160 ch, transposed layout ----
  // DMA: 60 (r,v) pairs, lane = px (0..63 -> xx = px-1); px 64,65 manual.
  #pragma unroll
  for (int i = 0; i < 15; ++i) {
    int pid = wave * 15 + i;
    int r = pid / 20, v = pid - r * 20;
    int yy = y - 1 + r;
    bool rowOK = (yy >= 0) && (yy < 64);
    const short* rowPtr = Pcur + (size_t)((b * 64 + yy) * 64) * CS + v * 8;
    const short* g = (rowOK && lane > 0) ? (rowPtr + (size_t)(lane - 1) * CS) : zp;
    // dst granule for lane L is base + L*16B (hardware); base = (r,v) slot start
    async_ld16(g - (size_t)lane * 8 + (size_t)lane * 8, halo + r * RPITCH + v * VPITCH);
    // NOTE: per-lane g computed above; LDS side is wave-uniform base.
    (void)g;
  }
  // The above must pass per-lane global addresses; rewrite explicitly:
  // (compilers keep per-lane vaddr; the loop body below does the real issue)
  // -- extra px 64,65 via plain ds_write --
  if (wave < 3 && lane < 40) {
    int r = wave, v = lane >> 1, pxi = 64 + (lane & 1);
    int yy = y - 1 + r;
    bool rowOK = (yy >= 0) && (yy < 64);
    short8 val = {0, 0, 0, 0, 0, 0, 0, 0};
    if (rowOK && pxi == 64)                       // xx = 63
      val = *(const short8*)(Pcur + (size_t)((b * 64 + yy) * 64 + 63) * CS + v * 8);
    *(short8*)(halo + r * RPITCH + v * VPITCH + pxi * 8) = val;
  }
  __syncthreads();

  // ---- accumulators: 16px x 128co per wave ----
  float4v acc[8];
  #pragma unroll
  for (int i = 0; i < 8; ++i) acc[i] = (float4v){0.f, 0.f, 0.f, 0.f};

  // B pointers: co(nf) = (nf>>1)*128 + nt*32 + (nf&1)*16 + ln15
  const short* bb[8];
  short8 bcur[8], bnxt[8];
  #pragma unroll
  for (int nf = 0; nf < 8; ++nf) {
    int co = (nf >> 1) * 128 + nt * 32 + (nf & 1) * 16 + ln15;
    bb[nf] = Wp + (size_t)co * KTOT + quad * 8;
    bcur[nf] = *(const short8*)(bb[nf]);          // ch0, tap0
  }

  int pxb = wave * 16 + ln15;
  for (int ch = 0; ch < 5; ++ch) {
    #pragma unroll
    for (int tap = 0; tap < 9; ++tap) {
      int dy = tap / 3, dx = tap - dy * 3;
      int ntap = (tap < 8) ? tap + 1 : 0;
      int nch = (tap < 8) ? ch : ((ch < 4) ? ch + 1 : ch);
      #pragma unroll
      for (int nf = 0; nf < 8; ++nf)
        bnxt[nf] = *(const short8*)(bb[nf] + ntap * CS + nch * 32);

      short8 af = *(const short8*)&halo[dy * RPITCH + (ch * 4 + quad) * VPITCH
                                        + (pxb + dx) * 8];
      #pragma unroll
      for (int nf = 0; nf < 8; ++nf)
        acc[nf] = __builtin_amdgcn_mfma_f32_16x16x32_f16(af, bcur[nf], acc[nf], 0, 0, 0);
      #pragma unroll
      for (int nf = 0; nf < 8; ++nf) bcur[nf] = bnxt[nf];
    }
  }

  // ---- epilogue: gates per (pixel, hc-half) ----
  int rowPix = (b * 64 + y) * 64;
  #pragma unroll
  for (int h = 0; h < 2; ++h) {
    int hc = nt * 32 + h * 16 + ln15;
    float bi = Bc0[hc], bff = Bc0[128 + hc], bo = Bc0[256 + hc], bg = Bc0[384 + hc];
    #pragma unroll
    for (int r = 0; r < 4; ++r) {
      int x = wave * 16 + quad * 4 + r;          // C/D row = quad*4 + reg
      int pix = rowPix + x;
      float zi = acc[0 + h][r] + bi;
      float zf = acc[2 + h][r] + bff;
      float zo = acc[4 + h][r] + bo;
      float zg = acc[6 + h][r] + bg;
      float cprev = C0[(size_t)pix * 128 + hc];
      float cn = sigf(zf) * cprev + sigf(zi) * tanhf(zg);
      float hn = sigf(zo) * tanhf(cn);
      C0[(size_t)pix * 128 + hc] = cn;
      Pnext[(size_t)pix * CS + 1 + hc] = f2hs(hn);
    }
  }
  if (nt == 0 && t < 11 && tid < 64) {
    Pnext[(size_t)(rowPix + tid) * CS] = Xc[(b * 12 + t + 1) * 4096 + y * 64 + tid];
  }
}

// ---- layer 1 (R11 verbatim): M=128px x N=48co, chunked staging. Grid 512. ----
__device__ __forceinline__ void stage_row32(const short* __restrict__ rowPtr, bool rowOK,
                                            short* dstRow, int lane,
                                            const short* __restrict__ zp) {
  #pragma unroll
  for (int j = 0; j < 4; ++j) {
    int e = j * 64 + lane;
    int px = e >> 2, v = e & 3;
    int xx = px - 1;
    const short* g = (rowOK && xx >= 0) ? (rowPtr + (size_t)xx * CS + v * 8) : zp;
    async_ld16(g, dstRow + e * 8);
  }
  if (lane < 8) {
    int px = 64 + (lane >> 2), v = lane & 3, xx = px - 1;
    short8 val = {0, 0, 0, 0, 0, 0, 0, 0};
    if (rowOK && xx < 64) val = *(const short8*)(rowPtr + (size_t)xx * CS + v * 8);
    *(short8*)(dstRow + px * 32 + v * 8) = val;
  }
}

__global__ __launch_bounds__(256, 2) void gemm_gate1(
    const short* __restrict__ Prd, short* __restrict__ Pwr,
    const short* __restrict__ Wp, const float* __restrict__ Bc1,
    float* __restrict__ C1, void* __restrict__ outp,
    const short* __restrict__ zp, const int* __restrict__ flagp, int t) {
  int bid = blockIdx.x;                        // 0..511
  int b = bid >> 5, y0 = (bid & 31) * 2;
  int tid = threadIdx.x, wave = tid >> 6, lane = tid & 63;
  int ln15 = lane & 15, quad = lane >> 4;
  int wr = wave >> 1, wh = wave & 1;
  int flagv = *flagp;

  __shared__ __align__(16) short halo[2 * 4 * 66 * 32];   // 33792 B

  float4v acc[2][3];
  #pragma unroll
  for (int i = 0; i < 2; ++i)
    #pragma unroll
    for (int j = 0; j < 3; ++j) acc[i][j] = (float4v){0.f, 0.f, 0.f, 0.f};

  int yy = y0 - 1 + wave;
  bool rowOK = (yy >= 0) && (yy < 64);
  const short* rowBase = Prd + (size_t)((b * 64 + yy) * 64) * CS;

  const short* wbase = Wp + (size_t)ln15 * KTOT + quad * 8;
  short8 bcur[3], bnxt[3];
  #pragma unroll
  for (int nf = 0; nf < 3; ++nf)
    bcur[nf] = *(const short8*)(wbase + (size_t)nf * 16 * KTOT);

  stage_row32(rowBase, rowOK, halo + wave * 2112, lane, zp);
  __syncthreads();

  for (int ch = 0; ch < 5; ++ch) {
    int c0 = ch * 32;
    const short* cur = halo + (ch & 1) * 8448;
    if (ch < 4)
      stage_row32(rowBase + c0 + 32, rowOK, halo + ((ch + 1) & 1) * 8448 + wave * 2112,
                  lane, zp);
    #pragma unroll
    for (int tap = 0; tap < 9; ++tap) {
      int dy = tap / 3, dx = tap - dy * 3;
      int ntap = (tap < 8) ? tap + 1 : 0;
      int nc0 = (tap < 8) ? c0 : ((ch < 4) ? c0 + 32 : c0);
      #pragma unroll
      for (int nf = 0; nf < 3; ++nf)
        bnxt[nf] = *(const short8*)(wbase + (size_t)nf * 16 * KTOT + ntap * CS + nc0);

      short8 af[2];
      #pragma unroll
      for (int mf = 0; mf < 2; ++mf)
        af[mf] = *(const short8*)&cur[((wr + dy) * 66 + wh * 32 + mf * 16 + ln15 + dx) * 32
                                      + quad * 8];
      #pragma unroll
      for (int nf = 0; nf < 3; ++nf)
        #pragma unroll
        for (int mf = 0; mf < 2; ++mf)
          acc[mf][nf] = __builtin_amdgcn_mfma_f32_16x16x32_f16(af[mf], bcur[nf], acc[mf][nf], 0, 0, 0);
      #pragma unroll
      for (int nf = 0; nf < 3; ++nf) bcur[nf] = bnxt[nf];
    }
    __syncthreads();
  }

  float* zbuf = (float*)halo;
  #pragma unroll
  for (int mf = 0; mf < 2; ++mf)
    #pragma unroll
    for (int nf = 0; nf < 3; ++nf)
      #pragma unroll
      for (int r = 0; r < 4; ++r) {
        int pxl = wr * 64 + wh * 32 + mf * 16 + quad * 4 + r;
        zbuf[pxl * 48 + nf * 16 + ln15] = acc[mf][nf][r];
      }
  __syncthreads();

  #pragma unroll
  for (int k = 0; k < 6; ++k) {
    int id = k * 256 + tid;
    int hc = id >> 7, pxl = id & 127;
    float zi = zbuf[pxl * 48 + hc]      + Bc1[hc];
    float zf = zbuf[pxl * 48 + 12 + hc] + Bc1[12 + hc];
    float zo = zbuf[pxl * 48 + 24 + hc] + Bc1[24 + hc];
    float zg = zbuf[pxl * 48 + 36 + hc] + Bc1[36 + hc];
    int y = y0 + (pxl >> 6), x = pxl & 63;
    int pix = (b * 64 + y) * 64 + x;
    float cprev = C1[(size_t)pix * 12 + hc];
    float cn = sigf(zf) * cprev + sigf(zi) * tanhf(zg);
    float hn = sigf(zo) * tanhf(cn);
    C1[(size_t)pix * 12 + hc] = cn;
    Pwr[(size_t)pix * CS + 129 + hc] = f2hs(hn);
    if (t == 11) {
      int oidx = (b * 12 + hc) * 4096 + y * 64 + x;
      if (flagv) ((float*)outp)[oidx] = hn;
      else ((short*)outp)[oidx] = f2bs(hn);
    }
  }
}

extern "C" void kernel_launch(void* const* d_in, const int* in_sizes, int n_in,
                              void* d_out, int out_size, void* d_ws, size_t ws_size,
                              hipStream_t stream) {
  const void* hist = d_in[0];                  // (16,12,4096,1)
  const void* W0 = d_in[2];                    // (512,129,3,3)
  const void* b0 = d_in[3];
  const void* W1 = d_in[4];                    // (48,140,3,3)
  const void* b1 = d_in[5];

  char* ws = (char*)d_ws;
  const size_t PszB = (size_t)16 * 4096 * CS * 2;     // 20,971,520
  short* P[2] = {(short*)ws, (short*)(ws + PszB)};
  float* C0 = (float*)(ws + 2 * PszB);                // 33,554,432
  const size_t C0e = 2 * PszB + 33554432;
  float* C1 = (float*)(ws + C0e);                     // 3,145,728
  const size_t C1e = C0e + 3145728;
  short* zp = (short*)(ws + C1e);                     // 256 B zero page
  const size_t zpe = C1e + 256;
  short* Xc = (short*)(ws + zpe);                     // 1,572,864
  const size_t Xce = zpe + 1572864;
  short* Wp0 = (short*)(ws + Xce);                    // 1,474,560
  const size_t W0e = Xce + (size_t)512 * KTOT * 2;
  short* Wp1 = (short*)(ws + W0e);                    // 138,240
  const size_t W1e = W0e + (size_t)48 * KTOT * 2;
  float* Bc0 = (float*)(ws + W1e);                    // 2048
  float* Bc1 = (float*)(ws + W1e + 2048);             // 192
  int* flag = (int*)(ws + W1e + 2048 + 192);          // total ~82 MiB

  hipMemsetAsync(ws, 0, zpe, stream);                 // P pair + C0 + C1 + zero page
  detect_dtype<<<1, 64, 0, stream>>>((const unsigned short*)W0, flag);
  canon_x<<<3072, 256, 0, stream>>>(hist, Xc, flag);
  canon_b<<<3, 256, 0, stream>>>(b0, b1, Bc0, Bc1, flag);
  prep_w0<<<(512 * KTOT + 255) / 256, 256, 0, stream>>>(W0, Wp0, flag);
  prep_w1<<<(48 * KTOT + 255) / 256, 256, 0, stream>>>(W1, Wp1, flag);
  fill_x0<<<256, 256, 0, stream>>>(Xc, P[0]);

  for (int t = 0; t < 12; ++t) {
    gemm_gate0<<<4096, 256, 0, stream>>>(P[t & 1], P[(t + 1) & 1], Wp0, Bc0, C0, Xc, zp, t);
    gemm_gate1<<<512, 256, 0, stream>>>(P[(t + 1) & 1], P[t & 1], Wp1, Bc1, C1,
                                        d_out, zp, flag, t);
  }
}

// Round 14
// 2465.878 us; speedup vs baseline: 2.3740x; 2.3740x over previous
//
#include <hip/hip_runtime.h>
#include <hip/hip_bf16.h>

// ConvLSTM (2 layers) on MI355X. R14: R11 fp16 pipeline (verified 2202us)
// with gate0 register diet: explicit B prefetch REMOVED (R6 proved it neutral;
// costs 32 VGPR) + __launch_bounds__(256,4) -> 4 blocks/CU (regs ~116 <= 128,
// LDS 4x33.8KB = 135KB < 160KB). Same verified 64x64 wave tile / K-loop.
// P (B,64,64,160) fp16: [x(1), h0(128), h1(12), pad(19)].
// gg0 t: P[t&1] -> P[(t+1)&1]; gg1 t: reads P[(t+1)&1], writes h1 -> P[t&1].

typedef __attribute__((ext_vector_type(8))) short short8;
typedef __attribute__((ext_vector_type(4))) float float4v;

#define CS 160
#define KTOT 1440         // 9*160

__device__ __forceinline__ float sigf(float x) { return 1.f / (1.f + __expf(-x)); }
__device__ __forceinline__ short f2hs(float v) {
  _Float16 h = (_Float16)v;
  return *(short*)&h;
}
__device__ __forceinline__ float bs2f(short s) {
  __hip_bfloat16 h; *(short*)&h = s; return __bfloat162float(h);
}
__device__ __forceinline__ short f2bs(float v) {
  __hip_bfloat16 h = __float2bfloat16(v);
  return *(short*)&h;
}

// async 16B global->LDS; per-lane lds ptr must equal uniform_base + lane*16
__device__ __forceinline__ void async_ld16(const short* g, short* l) {
  __builtin_amdgcn_global_load_lds(
      (const __attribute__((address_space(1))) unsigned int*)g,
      (__attribute__((address_space(3))) unsigned int*)l, 16, 0, 0);
}

// Stage one halo row (66 px x 32 ch) into LDS at dstRow (row-major, 32ch/px).
__device__ __forceinline__ void stage_row(const short* __restrict__ rowPtr, bool rowOK,
                                          short* dstRow, int lane,
                                          const short* __restrict__ zp) {
  #pragma unroll
  for (int j = 0; j < 4; ++j) {
    int e = j * 64 + lane;
    int px = e >> 2, v = e & 3;
    int xx = px - 1;
    const short* g = (rowOK && xx >= 0) ? (rowPtr + (size_t)xx * CS + v * 8) : zp;
    async_ld16(g, dstRow + e * 8);
  }
  if (lane < 8) {
    int px = 64 + (lane >> 2), v = lane & 3, xx = px - 1;
    short8 val = {0, 0, 0, 0, 0, 0, 0, 0};
    if (rowOK && xx < 64) val = *(const short8*)(rowPtr + (size_t)xx * CS + v * 8);
    *(short8*)(dstRow + px * 32 + v * 8) = val;
  }
}

// ---- dtype detect ----
__global__ void detect_dtype(const unsigned short* __restrict__ w0, int* __restrict__ flag) {
  int lane = threadIdx.x;
  int cnt = 0;
  for (int i = 0; i < 4; ++i) {
    unsigned short u = w0[2 * (lane + 64 * i)];
    int e = (u >> 7) & 0xFF;
    unsigned long long b = __ballot(e >= 0xC0);
    cnt += __popcll(b);
  }
  if (lane == 0) *flag = (cnt > 32) ? 1 : 0;   // 1 = fp32 inputs
}

// ---- canonicalize x -> fp16 shorts (bf16->fp16 exact; sanitized) ----
__global__ void canon_x(const void* __restrict__ hist, short* __restrict__ Xc,
                        const int* __restrict__ flag) {
  int i = blockIdx.x * 256 + threadIdx.x;      // < 786432
  float v = (*flag) ? ((const float*)hist)[i] : bs2f(((const short*)hist)[i]);
  if (!isfinite(v) || fabsf(v) > 1e4f) v = 0.f;
  Xc[i] = f2hs(v);
}

__global__ void canon_b(const void* __restrict__ b0, const void* __restrict__ b1,
                        float* __restrict__ Bc0, float* __restrict__ Bc1,
                        const int* __restrict__ flag) {
  int i = blockIdx.x * 256 + threadIdx.x;
  int fl = *flag;
  if (i < 512) {
    float v = fl ? ((const float*)b0)[i] : bs2f(((const short*)b0)[i]);
    if (!isfinite(v) || fabsf(v) > 1e4f) v = 0.f;
    Bc0[i] = v;
  } else if (i < 560) {
    int j = i - 512;
    float v = fl ? ((const float*)b1)[j] : bs2f(((const short*)b1)[j]);
    if (!isfinite(v) || fabsf(v) > 1e4f) v = 0.f;
    Bc1[j] = v;
  }
}

// layer0 W0 (512,129,3,3) -> fp16 Wp[co][tap*160+c]: P-ch 0=x, 1..128=h0, else 0.
__global__ void prep_w0(const void* __restrict__ W0, short* __restrict__ Wp,
                        const int* __restrict__ flag) {
  int i = blockIdx.x * 256 + threadIdx.x;
  if (i >= 512 * KTOT) return;
  int fl = *flag;
  int co = i / KTOT, k = i - co * KTOT;
  int tap = k / CS, c = k - tap * CS;
  int ci = -1;
  if (c == 0) ci = 0;
  else if (c <= 128) ci = c;
  float w = 0.f;
  if (ci >= 0) {
    int widx = (co * 129 + ci) * 9 + tap;
    w = fl ? ((const float*)W0)[widx] : bs2f(((const short*)W0)[widx]);
    if (!isfinite(w) || fabsf(w) > 1e4f) w = 0.f;
  }
  Wp[i] = f2hs(w);
}

// layer1 W1 (48,140,3,3) -> fp16: P-ch 1..128=h0, 129..140=h1, else 0.
__global__ void prep_w1(const void* __restrict__ W1, short* __restrict__ Wp,
                        const int* __restrict__ flag) {
  int i = blockIdx.x * 256 + threadIdx.x;
  if (i >= 48 * KTOT) return;
  int fl = *flag;
  int co = i / KTOT, k = i - co * KTOT;
  int tap = k / CS, c = k - tap * CS;
  int ci = -1;
  if (c >= 1 && c <= 140) ci = c - 1;
  float w = 0.f;
  if (ci >= 0) {
    int widx = (co * 140 + ci) * 9 + tap;
    w = fl ? ((const float*)W1)[widx] : bs2f(((const short*)W1)[widx]);
    if (!isfinite(w) || fabsf(w) > 1e4f) w = 0.f;
  }
  Wp[i] = f2hs(w);
}

__global__ void fill_x0(const short* __restrict__ Xc, short* __restrict__ P0) {
  int p = blockIdx.x * 256 + threadIdx.x;      // b*4096 + pix
  int b = p >> 12, pix = p & 4095;
  P0[(size_t)p * CS] = Xc[b * 12 * 4096 + pix];
}

// ---- layer 0: M=128px (2 rows) x N=128co (4 gates x 32 hc). Grid = 4 nt * 512 mt. ----
__global__ __launch_bounds__(256, 4) void gemm_gate0(
    const short* __restrict__ Pcur, short* __restrict__ Pnext,
    const short* __restrict__ Wp, const float* __restrict__ Bc0,
    float* __restrict__ C0, const short* __restrict__ Xc,
    const short* __restrict__ zp, int t) {
  int bx = blockIdx.x;
  int nt = bx >> 9, mt = bx & 511;             // consecutive blocks share nt (weight L2 reuse)
  int b = mt >> 5, y0 = (mt & 31) * 2;
  int tid = threadIdx.x, wave = tid >> 6, lane = tid & 63;
  int ln15 = lane & 15, quad = lane >> 4;
  int wm = wave & 1, wn = wave >> 1;
  int hc = nt * 32 + wn * 16 + ln15;

  __shared__ __align__(16) short halo[2 * 4 * 66 * 32];   // dbuf, 33792 B

  float4v acc[4][4];
  #pragma unroll
  for (int i = 0; i < 4; ++i)
    #pragma unroll
    for (int j = 0; j < 4; ++j) acc[i][j] = (float4v){0.f, 0.f, 0.f, 0.f};

  // B frag addr (g, tap, c0): wbase + g*128*KTOT + tap*CS + c0 (loads inline, no prefetch)
  const short* wbase = Wp + (size_t)hc * KTOT + quad * 8;

  int yy = y0 - 1 + wave;
  bool rowOK = (yy >= 0) && (yy < 64);
  const short* rowBase = Pcur + (size_t)((b * 64 + yy) * 64) * CS;

  stage_row(rowBase, rowOK, halo + wave * 2112, lane, zp);
  __syncthreads();

  for (int ch = 0; ch < 5; ++ch) {
    int c0 = ch * 32;
    const short* cur = halo + (ch & 1) * 8448;
    if (ch < 4)
      stage_row(rowBase + c0 + 32, rowOK, halo + ((ch + 1) & 1) * 8448 + wave * 2112,
                lane, zp);
    #pragma unroll
    for (int tap = 0; tap < 9; ++tap) {
      int dy = tap / 3, dx = tap - dy * 3;
      short8 af[4];
      #pragma unroll
      for (int mf = 0; mf < 4; ++mf)
        af[mf] = *(const short8*)&cur[((wm + dy) * 66 + mf * 16 + ln15 + dx) * 32 + quad * 8];
      #pragma unroll
      for (int g = 0; g < 4; ++g) {
        short8 bf = *(const short8*)(wbase + (size_t)g * 128 * KTOT + tap * CS + c0);
        #pragma unroll
        for (int mf = 0; mf < 4; ++mf)
          acc[mf][g] = __builtin_amdgcn_mfma_f32_16x16x32_f16(af[mf], bf, acc[mf][g], 0, 0, 0);
      }
    }
    __syncthreads();
  }

  // epilogue: all 4 gates in-register per (pix,hc)
  float bi = Bc0[hc], bff = Bc0[128 + hc], bo = Bc0[256 + hc], bg = Bc0[384 + hc];
  int rowPix = (b * 64 + y0 + wm) * 64;
  #pragma unroll
  for (int mf = 0; mf < 4; ++mf) {
    #pragma unroll
    for (int r = 0; r < 4; ++r) {
      int x = mf * 16 + quad * 4 + r;          // C/D row = quad*4 + reg
      int pix = rowPix + x;
      float zi = acc[mf][0][r] + bi;
      float zf = acc[mf][1][r] + bff;
      float zo = acc[mf][2][r] + bo;
      float zg = acc[mf][3][r] + bg;
      float cprev = C0[(size_t)pix * 128 + hc];
      float cn = sigf(zf) * cprev + sigf(zi) * tanhf(zg);
      float hn = sigf(zo) * tanhf(cn);
      C0[(size_t)pix * 128 + hc] = cn;
      Pnext[(size_t)pix * CS + 1 + hc] = f2hs(hn);
    }
  }
  if (nt == 0 && t < 11 && tid < 128) {
    int rr = tid >> 6, x = tid & 63;
    int yw = y0 + rr;
    Pnext[(size_t)((b * 64 + yw) * 64 + x) * CS] = Xc[(b * 12 + t + 1) * 4096 + yw * 64 + x];
  }
}

// ---- layer 1 (R11 verbatim): M=128px x N=48co. Grid 512. ----
__global__ __launch_bounds__(256, 2) void gemm_gate1(
    const short* __restrict__ Prd, short* __restrict__ Pwr,
    const short* __restrict__ Wp, const float* __restrict__ Bc1,
    float* __restrict__ C1, void* __restrict__ outp,
    const short* __restrict__ zp, const int* __restrict__ flagp, int t) {
  int bid = blockIdx.x;                        // 0..511
  int b = bid >> 5, y0 = (bid & 31) * 2;
  int tid = threadIdx.x, wave = tid >> 6, lane = tid & 63;
  int ln15 = lane & 15, quad = lane >> 4;
  int wr = wave >> 1, wh = wave & 1;
  int flagv = *flagp;

  __shared__ __align__(16) short halo[2 * 4 * 66 * 32];   // 33792 B

  float4v acc[2][3];
  #pragma unroll
  for (int i = 0; i < 2; ++i)
    #pragma unroll
    for (int j = 0; j < 3; ++j) acc[i][j] = (float4v){0.f, 0.f, 0.f, 0.f};

  int yy = y0 - 1 + wave;
  bool rowOK = (yy >= 0) && (yy < 64);
  const short* rowBase = Prd + (size_t)((b * 64 + yy) * 64) * CS;

  const short* wbase = Wp + (size_t)ln15 * KTOT + quad * 8;
  short8 bcur[3], bnxt[3];
  #pragma unroll
  for (int nf = 0; nf < 3; ++nf)
    bcur[nf] = *(const short8*)(wbase + (size_t)nf * 16 * KTOT);

  stage_row(rowBase, rowOK, halo + wave * 2112, lane, zp);
  __syncthreads();

  for (int ch = 0; ch < 5; ++ch) {
    int c0 = ch * 32;
    const short* cur = halo + (ch & 1) * 8448;
    if (ch < 4)
      stage_row(rowBase + c0 + 32, rowOK, halo + ((ch + 1) & 1) * 8448 + wave * 2112,
                lane, zp);
    #pragma unroll
    for (int tap = 0; tap < 9; ++tap) {
      int dy = tap / 3, dx = tap - dy * 3;
      int ntap = (tap < 8) ? tap + 1 : 0;
      int nc0 = (tap < 8) ? c0 : ((ch < 4) ? c0 + 32 : c0);
      #pragma unroll
      for (int nf = 0; nf < 3; ++nf)
        bnxt[nf] = *(const short8*)(wbase + (size_t)nf * 16 * KTOT + ntap * CS + nc0);

      short8 af[2];
      #pragma unroll
      for (int mf = 0; mf < 2; ++mf)
        af[mf] = *(const short8*)&cur[((wr + dy) * 66 + wh * 32 + mf * 16 + ln15 + dx) * 32
                                      + quad * 8];
      #pragma unroll
      for (int nf = 0; nf < 3; ++nf)
        #pragma unroll
        for (int mf = 0; mf < 2; ++mf)
          acc[mf][nf] = __builtin_amdgcn_mfma_f32_16x16x32_f16(af[mf], bcur[nf], acc[mf][nf], 0, 0, 0);
      #pragma unroll
      for (int nf = 0; nf < 3; ++nf) bcur[nf] = bnxt[nf];
    }
    __syncthreads();
  }

  // z -> LDS (reuse halo: 128*48 fp32 = 24576 B), then gate pass
  float* zbuf = (float*)halo;
  #pragma unroll
  for (int mf = 0; mf < 2; ++mf)
    #pragma unroll
    for (int nf = 0; nf < 3; ++nf)
      #pragma unroll
      for (int r = 0; r < 4; ++r) {
        int pxl = wr * 64 + wh * 32 + mf * 16 + quad * 4 + r;
        zbuf[pxl * 48 + nf * 16 + ln15] = acc[mf][nf][r];
      }
  __syncthreads();

  #pragma unroll
  for (int k = 0; k < 6; ++k) {
    int id = k * 256 + tid;
    int hc = id >> 7, pxl = id & 127;
    float zi = zbuf[pxl * 48 + hc]      + Bc1[hc];
    float zf = zbuf[pxl * 48 + 12 + hc] + Bc1[12 + hc];
    float zo = zbuf[pxl * 48 + 24 + hc] + Bc1[24 + hc];
    float zg = zbuf[pxl * 48 + 36 + hc] + Bc1[36 + hc];
    int y = y0 + (pxl >> 6), x = pxl & 63;
    int pix = (b * 64 + y) * 64 + x;
    float cprev = C1[(size_t)pix * 12 + hc];
    float cn = sigf(zf) * cprev + sigf(zi) * tanhf(zg);
    float hn = sigf(zo) * tanhf(cn);
    C1[(size_t)pix * 12 + hc] = cn;
    Pwr[(size_t)pix * CS + 129 + hc] = f2hs(hn);
    if (t == 11) {
      int oidx = (b * 12 + hc) * 4096 + y * 64 + x;
      if (flagv) ((float*)outp)[oidx] = hn;
      else ((short*)outp)[oidx] = f2bs(hn);
    }
  }
}

extern "C" void kernel_launch(void* const* d_in, const int* in_sizes, int n_in,
                              void* d_out, int out_size, void* d_ws, size_t ws_size,
                              hipStream_t stream) {
  const void* hist = d_in[0];                  // (16,12,4096,1)
  const void* W0 = d_in[2];                    // (512,129,3,3)
  const void* b0 = d_in[3];
  const void* W1 = d_in[4];                    // (48,140,3,3)
  const void* b1 = d_in[5];

  char* ws = (char*)d_ws;
  const size_t PszB = (size_t)16 * 4096 * CS * 2;     // 20,971,520
  short* P[2] = {(short*)ws, (short*)(ws + PszB)};
  float* C0 = (float*)(ws + 2 * PszB);                // 33,554,432
  const size_t C0e = 2 * PszB + 33554432;
  float* C1 = (float*)(ws + C0e);                     // 3,145,728
  const size_t C1e = C0e + 3145728;
  short* zp = (short*)(ws + C1e);                     // 256 B zero page
  const size_t zpe = C1e + 256;
  short* Xc = (short*)(ws + zpe);                     // 1,572,864
  const size_t Xce = zpe + 1572864;
  short* Wp0 = (short*)(ws + Xce);                    // 1,474,560
  const size_t W0e = Xce + (size_t)512 * KTOT * 2;
  short* Wp1 = (short*)(ws + W0e);                    // 138,240
  const size_t W1e = W0e + (size_t)48 * KTOT * 2;
  float* Bc0 = (float*)(ws + W1e);                    // 2048
  float* Bc1 = (float*)(ws + W1e + 2048);             // 192
  int* flag = (int*)(ws + W1e + 2048 + 192);          // total ~82 MiB

  hipMemsetAsync(ws, 0, zpe, stream);                 // P pair + C0 + C1 + zero page
  detect_dtype<<<1, 64, 0, stream>>>((const unsigned short*)W0, flag);
  canon_x<<<3072, 256, 0, stream>>>(hist, Xc, flag);
  canon_b<<<3, 256, 0, stream>>>(b0, b1, Bc0, Bc1, flag);
  prep_w0<<<(512 * KTOT + 255) / 256, 256, 0, stream>>>(W0, Wp0, flag);
  prep_w1<<<(48 * KTOT + 255) / 256, 256, 0, stream>>>(W1, Wp1, flag);
  fill_x0<<<256, 256, 0, stream>>>(Xc, P[0]);

  for (int t = 0; t < 12; ++t) {
    gemm_gate0<<<2048, 256, 0, stream>>>(P[t & 1], P[(t + 1) & 1], Wp0, Bc0, C0, Xc, zp, t);
    gemm_gate1<<<512, 256, 0, stream>>>(P[(t + 1) & 1], P[t & 1], Wp1, Bc1, C1,
                                        d_out, zp, flag, t);
  }
}

// Round 15
// 2431.080 us; speedup vs baseline: 2.4080x; 1.0143x over previous
//
#include <hip/hip_runtime.h>
#include <hip/hip_bf16.h>

// ConvLSTM (2 layers) on MI355X. R15 = R11 (verified 2202us) with ONE change:
// gemm_gate0 __launch_bounds__(256,3) -> 3 blocks/CU (regs 84+64=148 <= 170,
// LDS 3x33.8KB = 101KB < 160KB). R14's (256,4) spilled (cap 128 < 148 needed:
// VGPR forced to 64, FETCH/WRITE +90MB scratch traffic); (256,3) is the clean
// occupancy experiment. Everything else byte-identical to R11.
// P (B,64,64,160) fp16: [x(1), h0(128), h1(12), pad(19)].
// gg0 t: P[t&1] -> P[(t+1)&1]; gg1 t: reads P[(t+1)&1], writes h1 -> P[t&1].

typedef __attribute__((ext_vector_type(8))) short short8;
typedef __attribute__((ext_vector_type(4))) float float4v;

#define CS 160
#define KTOT 1440         // 9*160

__device__ __forceinline__ float sigf(float x) { return 1.f / (1.f + __expf(-x)); }
__device__ __forceinline__ short f2hs(float v) {
  _Float16 h = (_Float16)v;
  return *(short*)&h;
}
__device__ __forceinline__ float bs2f(short s) {
  __hip_bfloat16 h; *(short*)&h = s; return __bfloat162float(h);
}
__device__ __forceinline__ short f2bs(float v) {
  __hip_bfloat16 h = __float2bfloat16(v);
  return *(short*)&h;
}

// async 16B global->LDS; per-lane lds ptr must equal uniform_base + lane*16
__device__ __forceinline__ void async_ld16(const short* g, short* l) {
  __builtin_amdgcn_global_load_lds(
      (const __attribute__((address_space(1))) unsigned int*)g,
      (__attribute__((address_space(3))) unsigned int*)l, 16, 0, 0);
}

// Stage one halo row (66 px x 32 ch) into LDS at dstRow (row-major, 32ch/px).
__device__ __forceinline__ void stage_row(const short* __restrict__ rowPtr, bool rowOK,
                                          short* dstRow, int lane,
                                          const short* __restrict__ zp) {
  #pragma unroll
  for (int j = 0; j < 4; ++j) {
    int e = j * 64 + lane;
    int px = e >> 2, v = e & 3;
    int xx = px - 1;
    const short* g = (rowOK && xx >= 0) ? (rowPtr + (size_t)xx * CS + v * 8) : zp;
    async_ld16(g, dstRow + e * 8);
  }
  if (lane < 8) {
    int px = 64 + (lane >> 2), v = lane & 3, xx = px - 1;
    short8 val = {0, 0, 0, 0, 0, 0, 0, 0};
    if (rowOK && xx < 64) val = *(const short8*)(rowPtr + (size_t)xx * CS + v * 8);
    *(short8*)(dstRow + px * 32 + v * 8) = val;
  }
}

// ---- dtype detect ----
__global__ void detect_dtype(const unsigned short* __restrict__ w0, int* __restrict__ flag) {
  int lane = threadIdx.x;
  int cnt = 0;
  for (int i = 0; i < 4; ++i) {
    unsigned short u = w0[2 * (lane + 64 * i)];
    int e = (u >> 7) & 0xFF;
    unsigned long long b = __ballot(e >= 0xC0);
    cnt += __popcll(b);
  }
  if (lane == 0) *flag = (cnt > 32) ? 1 : 0;   // 1 = fp32 inputs
}

// ---- canonicalize x -> fp16 shorts (bf16->fp16 exact; sanitized) ----
__global__ void canon_x(const void* __restrict__ hist, short* __restrict__ Xc,
                        const int* __restrict__ flag) {
  int i = blockIdx.x * 256 + threadIdx.x;      // < 786432
  float v = (*flag) ? ((const float*)hist)[i] : bs2f(((const short*)hist)[i]);
  if (!isfinite(v) || fabsf(v) > 1e4f) v = 0.f;
  Xc[i] = f2hs(v);
}

__global__ void canon_b(const void* __restrict__ b0, const void* __restrict__ b1,
                        float* __restrict__ Bc0, float* __restrict__ Bc1,
                        const int* __restrict__ flag) {
  int i = blockIdx.x * 256 + threadIdx.x;
  int fl = *flag;
  if (i < 512) {
    float v = fl ? ((const float*)b0)[i] : bs2f(((const short*)b0)[i]);
    if (!isfinite(v) || fabsf(v) > 1e4f) v = 0.f;
    Bc0[i] = v;
  } else if (i < 560) {
    int j = i - 512;
    float v = fl ? ((const float*)b1)[j] : bs2f(((const short*)b1)[j]);
    if (!isfinite(v) || fabsf(v) > 1e4f) v = 0.f;
    Bc1[j] = v;
  }
}

// layer0 W0 (512,129,3,3) -> fp16 Wp[co][tap*160+c]: P-ch 0=x, 1..128=h0, else 0.
__global__ void prep_w0(const void* __restrict__ W0, short* __restrict__ Wp,
                        const int* __restrict__ flag) {
  int i = blockIdx.x * 256 + threadIdx.x;
  if (i >= 512 * KTOT) return;
  int fl = *flag;
  int co = i / KTOT, k = i - co * KTOT;
  int tap = k / CS, c = k - tap * CS;
  int ci = -1;
  if (c == 0) ci = 0;
  else if (c <= 128) ci = c;
  float w = 0.f;
  if (ci >= 0) {
    int widx = (co * 129 + ci) * 9 + tap;
    w = fl ? ((const float*)W0)[widx] : bs2f(((const short*)W0)[widx]);
    if (!isfinite(w) || fabsf(w) > 1e4f) w = 0.f;
  }
  Wp[i] = f2hs(w);
}

// layer1 W1 (48,140,3,3) -> fp16: P-ch 1..128=h0, 129..140=h1, else 0.
__global__ void prep_w1(const void* __restrict__ W1, short* __restrict__ Wp,
                        const int* __restrict__ flag) {
  int i = blockIdx.x * 256 + threadIdx.x;
  if (i >= 48 * KTOT) return;
  int fl = *flag;
  int co = i / KTOT, k = i - co * KTOT;
  int tap = k / CS, c = k - tap * CS;
  int ci = -1;
  if (c >= 1 && c <= 140) ci = c - 1;
  float w = 0.f;
  if (ci >= 0) {
    int widx = (co * 140 + ci) * 9 + tap;
    w = fl ? ((const float*)W1)[widx] : bs2f(((const short*)W1)[widx]);
    if (!isfinite(w) || fabsf(w) > 1e4f) w = 0.f;
  }
  Wp[i] = f2hs(w);
}

__global__ void fill_x0(const short* __restrict__ Xc, short* __restrict__ P0) {
  int p = blockIdx.x * 256 + threadIdx.x;      // b*4096 + pix
  int b = p >> 12, pix = p & 4095;
  P0[(size_t)p * CS] = Xc[b * 12 * 4096 + pix];
}

// ---- layer 0: M=128px (2 rows) x N=128co (4 gates x 32 hc). Grid = 4 nt * 512 mt. ----
__global__ __launch_bounds__(256, 3) void gemm_gate0(
    const short* __restrict__ Pcur, short* __restrict__ Pnext,
    const short* __restrict__ Wp, const float* __restrict__ Bc0,
    float* __restrict__ C0, const short* __restrict__ Xc,
    const short* __restrict__ zp, int t) {
  int bx = blockIdx.x;
  int nt = bx >> 9, mt = bx & 511;             // consecutive blocks share nt (weight L2 reuse)
  int b = mt >> 5, y0 = (mt & 31) * 2;
  int tid = threadIdx.x, wave = tid >> 6, lane = tid & 63;
  int ln15 = lane & 15, quad = lane >> 4;
  int wm = wave & 1, wn = wave >> 1;
  int hc = nt * 32 + wn * 16 + ln15;

  __shared__ __align__(16) short halo[2 * 4 * 66 * 32];   // dbuf, 33792 B

  float4v acc[4][4];
  #pragma unroll
  for (int i = 0; i < 4; ++i)
    #pragma unroll
    for (int j = 0; j < 4; ++j) acc[i][j] = (float4v){0.f, 0.f, 0.f, 0.f};

  // B frag addr (g, tap, c0): wbase + g*128*KTOT + tap*CS + c0
  const short* wbase = Wp + (size_t)hc * KTOT + quad * 8;
  short8 bcur[4], bnxt[4];
  #pragma unroll
  for (int g = 0; g < 4; ++g)
    bcur[g] = *(const short8*)(wbase + (size_t)g * 128 * KTOT);

  int yy = y0 - 1 + wave;
  bool rowOK = (yy >= 0) && (yy < 64);
  const short* rowBase = Pcur + (size_t)((b * 64 + yy) * 64) * CS;

  stage_row(rowBase, rowOK, halo + wave * 2112, lane, zp);
  __syncthreads();

  for (int ch = 0; ch < 5; ++ch) {
    int c0 = ch * 32;
    const short* cur = halo + (ch & 1) * 8448;
    if (ch < 4)
      stage_row(rowBase + c0 + 32, rowOK, halo + ((ch + 1) & 1) * 8448 + wave * 2112,
                lane, zp);
    #pragma unroll
    for (int tap = 0; tap < 9; ++tap) {
      int dy = tap / 3, dx = tap - dy * 3;
      // prefetch next tap's (or next chunk's tap-0) B fragments
      int ntap = (tap < 8) ? tap + 1 : 0;
      int nc0 = (tap < 8) ? c0 : ((ch < 4) ? c0 + 32 : c0);
      #pragma unroll
      for (int g = 0; g < 4; ++g)
        bnxt[g] = *(const short8*)(wbase + (size_t)g * 128 * KTOT + ntap * CS + nc0);

      short8 af[4];
      #pragma unroll
      for (int mf = 0; mf < 4; ++mf)
        af[mf] = *(const short8*)&cur[((wm + dy) * 66 + mf * 16 + ln15 + dx) * 32 + quad * 8];
      #pragma unroll
      for (int g = 0; g < 4; ++g)
        #pragma unroll
        for (int mf = 0; mf < 4; ++mf)
          acc[mf][g] = __builtin_amdgcn_mfma_f32_16x16x32_f16(af[mf], bcur[g], acc[mf][g], 0, 0, 0);
      #pragma unroll
      for (int g = 0; g < 4; ++g) bcur[g] = bnxt[g];
    }
    __syncthreads();
  }

  // epilogue: all 4 gates in-register per (pix,hc)
  float bi = Bc0[hc], bff = Bc0[128 + hc], bo = Bc0[256 + hc], bg = Bc0[384 + hc];
  int rowPix = (b * 64 + y0 + wm) * 64;
  #pragma unroll
  for (int mf = 0; mf < 4; ++mf) {
    #pragma unroll
    for (int r = 0; r < 4; ++r) {
      int x = mf * 16 + quad * 4 + r;          // C/D row = quad*4 + reg
      int pix = rowPix + x;
      float zi = acc[mf][0][r] + bi;
      float zf = acc[mf][1][r] + bff;
      float zo = acc[mf][2][r] + bo;
      float zg = acc[mf][3][r] + bg;
      float cprev = C0[(size_t)pix * 128 + hc];
      float cn = sigf(zf) * cprev + sigf(zi) * tanhf(zg);
      float hn = sigf(zo) * tanhf(cn);
      C0[(size_t)pix * 128 + hc] = cn;
      Pnext[(size_t)pix * CS + 1 + hc] = f2hs(hn);
    }
  }
  if (nt == 0 && t < 11 && tid < 128) {
    int rr = tid >> 6, x = tid & 63;
    int yw = y0 + rr;
    Pnext[(size_t)((b * 64 + yw) * 64 + x) * CS] = Xc[(b * 12 + t + 1) * 4096 + yw * 64 + x];
  }
}

// ---- layer 1 (R11 verbatim): M=128px x N=48co. Grid 512. ----
__global__ __launch_bounds__(256, 2) void gemm_gate1(
    const short* __restrict__ Prd, short* __restrict__ Pwr,
    const short* __restrict__ Wp, const float* __restrict__ Bc1,
    float* __restrict__ C1, void* __restrict__ outp,
    const short* __restrict__ zp, const int* __restrict__ flagp, int t) {
  int bid = blockIdx.x;                        // 0..511
  int b = bid >> 5, y0 = (bid & 31) * 2;
  int tid = threadIdx.x, wave = tid >> 6, lane = tid & 63;
  int ln15 = lane & 15, quad = lane >> 4;
  int wr = wave >> 1, wh = wave & 1;
  int flagv = *flagp;

  __shared__ __align__(16) short halo[2 * 4 * 66 * 32];   // 33792 B

  float4v acc[2][3];
  #pragma unroll
  for (int i = 0; i < 2; ++i)
    #pragma unroll
    for (int j = 0; j < 3; ++j) acc[i][j] = (float4v){0.f, 0.f, 0.f, 0.f};

  int yy = y0 - 1 + wave;
  bool rowOK = (yy >= 0) && (yy < 64);
  const short* rowBase = Prd + (size_t)((b * 64 + yy) * 64) * CS;

  const short* wbase = Wp + (size_t)ln15 * KTOT + quad * 8;
  short8 bcur[3], bnxt[3];
  #pragma unroll
  for (int nf = 0; nf < 3; ++nf)
    bcur[nf] = *(const short8*)(wbase + (size_t)nf * 16 * KTOT);

  stage_row(rowBase, rowOK, halo + wave * 2112, lane, zp);
  __syncthreads();

  for (int ch = 0; ch < 5; ++ch) {
    int c0 = ch * 32;
    const short* cur = halo + (ch & 1) * 8448;
    if (ch < 4)
      stage_row(rowBase + c0 + 32, rowOK, halo + ((ch + 1) & 1) * 8448 + wave * 2112,
                lane, zp);
    #pragma unroll
    for (int tap = 0; tap < 9; ++tap) {
      int dy = tap / 3, dx = tap - dy * 3;
      int ntap = (tap < 8) ? tap + 1 : 0;
      int nc0 = (tap < 8) ? c0 : ((ch < 4) ? c0 + 32 : c0);
      #pragma unroll
      for (int nf = 0; nf < 3; ++nf)
        bnxt[nf] = *(const short8*)(wbase + (size_t)nf * 16 * KTOT + ntap * CS + nc0);

      short8 af[2];
      #pragma unroll
      for (int mf = 0; mf < 2; ++mf)
        af[mf] = *(const short8*)&cur[((wr + dy) * 66 + wh * 32 + mf * 16 + ln15 + dx) * 32
                                      + quad * 8];
      #pragma unroll
      for (int nf = 0; nf < 3; ++nf)
        #pragma unroll
        for (int mf = 0; mf < 2; ++mf)
          acc[mf][nf] = __builtin_amdgcn_mfma_f32_16x16x32_f16(af[mf], bcur[nf], acc[mf][nf], 0, 0, 0);
      #pragma unroll
      for (int nf = 0; nf < 3; ++nf) bcur[nf] = bnxt[nf];
    }
    __syncthreads();
  }

  // z -> LDS (reuse halo: 128*48 fp32 = 24576 B), then gate pass
  float* zbuf = (float*)halo;
  #pragma unroll
  for (int mf = 0; mf < 2; ++mf)
    #pragma unroll
    for (int nf = 0; nf < 3; ++nf)
      #pragma unroll
      for (int r = 0; r < 4; ++r) {
        int pxl = wr * 64 + wh * 32 + mf * 16 + quad * 4 + r;
        zbuf[pxl * 48 + nf * 16 + ln15] = acc[mf][nf][r];
      }
  __syncthreads();

  #pragma unroll
  for (int k = 0; k < 6; ++k) {
    int id = k * 256 + tid;
    int hc = id >> 7, pxl = id & 127;
    float zi = zbuf[pxl * 48 + hc]      + Bc1[hc];
    float zf = zbuf[pxl * 48 + 12 + hc] + Bc1[12 + hc];
    float zo = zbuf[pxl * 48 + 24 + hc] + Bc1[24 + hc];
    float zg = zbuf[pxl * 48 + 36 + hc] + Bc1[36 + hc];
    int y = y0 + (pxl >> 6), x = pxl & 63;
    int pix = (b * 64 + y) * 64 + x;
    float cprev = C1[(size_t)pix * 12 + hc];
    float cn = sigf(zf) * cprev + sigf(zi) * tanhf(zg);
    float hn = sigf(zo) * tanhf(cn);
    C1[(size_t)pix * 12 + hc] = cn;
    Pwr[(size_t)pix * CS + 129 + hc] = f2hs(hn);
    if (t == 11) {
      int oidx = (b * 12 + hc) * 4096 + y * 64 + x;
      if (flagv) ((float*)outp)[oidx] = hn;
      else ((short*)outp)[oidx] = f2bs(hn);
    }
  }
}

extern "C" void kernel_launch(void* const* d_in, const int* in_sizes, int n_in,
                              void* d_out, int out_size, void* d_ws, size_t ws_size,
                              hipStream_t stream) {
  const void* hist = d_in[0];                  // (16,12,4096,1)
  const void* W0 = d_in[2];                    // (512,129,3,3)
  const void* b0 = d_in[3];
  const void* W1 = d_in[4];                    // (48,140,3,3)
  const void* b1 = d_in[5];

  char* ws = (char*)d_ws;
  const size_t PszB = (size_t)16 * 4096 * CS * 2;     // 20,971,520
  short* P[2] = {(short*)ws, (short*)(ws + PszB)};
  float* C0 = (float*)(ws + 2 * PszB);                // 33,554,432
  const size_t C0e = 2 * PszB + 33554432;
  float* C1 = (float*)(ws + C0e);                     // 3,145,728
  const size_t C1e = C0e + 3145728;
  short* zp = (short*)(ws + C1e);                     // 256 B zero page
  const size_t zpe = C1e + 256;
  short* Xc = (short*)(ws + zpe);                     // 1,572,864
  const size_t Xce = zpe + 1572864;
  short* Wp0 = (short*)(ws + Xce);                    // 1,474,560
  const size_t W0e = Xce + (size_t)512 * KTOT * 2;
  short* Wp1 = (short*)(ws + W0e);                    // 138,240
  const size_t W1e = W0e + (size_t)48 * KTOT * 2;
  float* Bc0 = (float*)(ws + W1e);                    // 2048
  float* Bc1 = (float*)(ws + W1e + 2048);             // 192
  int* flag = (int*)(ws + W1e + 2048 + 192);          // total ~82 MiB

  hipMemsetAsync(ws, 0, zpe, stream);                 // P pair + C0 + C1 + zero page
  detect_dtype<<<1, 64, 0, stream>>>((const unsigned short*)W0, flag);
  canon_x<<<3072, 256, 0, stream>>>(hist, Xc, flag);
  canon_b<<<3, 256, 0, stream>>>(b0, b1, Bc0, Bc1, flag);
  prep_w0<<<(512 * KTOT + 255) / 256, 256, 0, stream>>>(W0, Wp0, flag);
  prep_w1<<<(48 * KTOT + 255) / 256, 256, 0, stream>>>(W1, Wp1, flag);
  fill_x0<<<256, 256, 0, stream>>>(Xc, P[0]);

  for (int t = 0; t < 12; ++t) {
    gemm_gate0<<<2048, 256, 0, stream>>>(P[t & 1], P[(t + 1) & 1], Wp0, Bc0, C0, Xc, zp, t);
    gemm_gate1<<<512, 256, 0, stream>>>(P[(t + 1) & 1], P[t & 1], Wp1, Bc1, C1,
                                        d_out, zp, flag, t);
  }
}

// Round 16
// 2309.696 us; speedup vs baseline: 2.5345x; 1.0526x over previous
//
#include <hip/hip_runtime.h>
#include <hip/hip_bf16.h>

// ConvLSTM (2 layers) on MI355X. R16 = R11 base (verified 2202us, (256,2)) +
//  (a) gate0 B-weight DEPTH-3 ring prefetch bb[3][4] (distance ~500cyc > L2
//      latency; R11's distance-1 stalled every tap -> MfmaUtil 25%);
//  (b) t=0 specialized VALU kernel gate0_t0 (h==0 -> 1-channel conv), replaces
//      a full 157us MFMA dispatch; fill_x0 dropped (t0 kernel writes x(1)).
// P (B,64,64,160) fp16: [x(1), h0(128), h1(12), pad(19)].
// gg0 t: P[t&1] -> P[(t+1)&1]; gg1 t: reads P[(t+1)&1], writes h1 -> P[t&1].

typedef __attribute__((ext_vector_type(8))) short short8;
typedef __attribute__((ext_vector_type(4))) float float4v;

#define CS 160
#define KTOT 1440         // 9*160

__device__ __forceinline__ float sigf(float x) { return 1.f / (1.f + __expf(-x)); }
__device__ __forceinline__ short f2hs(float v) {
  _Float16 h = (_Float16)v;
  return *(short*)&h;
}
__device__ __forceinline__ float hs2f(short s) {
  _Float16 h; *(short*)&h = s; return (float)h;
}
__device__ __forceinline__ float bs2f(short s) {
  __hip_bfloat16 h; *(short*)&h = s; return __bfloat162float(h);
}
__device__ __forceinline__ short f2bs(float v) {
  __hip_bfloat16 h = __float2bfloat16(v);
  return *(short*)&h;
}

// async 16B global->LDS; per-lane lds ptr must equal uniform_base + lane*16
__device__ __forceinline__ void async_ld16(const short* g, short* l) {
  __builtin_amdgcn_global_load_lds(
      (const __attribute__((address_space(1))) unsigned int*)g,
      (__attribute__((address_space(3))) unsigned int*)l, 16, 0, 0);
}

// Stage one halo row (66 px x 32 ch) into LDS at dstRow (row-major, 32ch/px).
__device__ __forceinline__ void stage_row(const short* __restrict__ rowPtr, bool rowOK,
                                          short* dstRow, int lane,
                                          const short* __restrict__ zp) {
  #pragma unroll
  for (int j = 0; j < 4; ++j) {
    int e = j * 64 + lane;
    int px = e >> 2, v = e & 3;
    int xx = px - 1;
    const short* g = (rowOK && xx >= 0) ? (rowPtr + (size_t)xx * CS + v * 8) : zp;
    async_ld16(g, dstRow + e * 8);
  }
  if (lane < 8) {
    int px = 64 + (lane >> 2), v = lane & 3, xx = px - 1;
    short8 val = {0, 0, 0, 0, 0, 0, 0, 0};
    if (rowOK && xx < 64) val = *(const short8*)(rowPtr + (size_t)xx * CS + v * 8);
    *(short8*)(dstRow + px * 32 + v * 8) = val;
  }
}

// ---- dtype detect ----
__global__ void detect_dtype(const unsigned short* __restrict__ w0, int* __restrict__ flag) {
  int lane = threadIdx.x;
  int cnt = 0;
  for (int i = 0; i < 4; ++i) {
    unsigned short u = w0[2 * (lane + 64 * i)];
    int e = (u >> 7) & 0xFF;
    unsigned long long b = __ballot(e >= 0xC0);
    cnt += __popcll(b);
  }
  if (lane == 0) *flag = (cnt > 32) ? 1 : 0;   // 1 = fp32 inputs
}

// ---- canonicalize x -> fp16 shorts (bf16->fp16 exact; sanitized) ----
__global__ void canon_x(const void* __restrict__ hist, short* __restrict__ Xc,
                        const int* __restrict__ flag) {
  int i = blockIdx.x * 256 + threadIdx.x;      // < 786432
  float v = (*flag) ? ((const float*)hist)[i] : bs2f(((const short*)hist)[i]);
  if (!isfinite(v) || fabsf(v) > 1e4f) v = 0.f;
  Xc[i] = f2hs(v);
}

__global__ void canon_b(const void* __restrict__ b0, const void* __restrict__ b1,
                        float* __restrict__ Bc0, float* __restrict__ Bc1,
                        const int* __restrict__ flag) {
  int i = blockIdx.x * 256 + threadIdx.x;
  int fl = *flag;
  if (i < 512) {
    float v = fl ? ((const float*)b0)[i] : bs2f(((const short*)b0)[i]);
    if (!isfinite(v) || fabsf(v) > 1e4f) v = 0.f;
    Bc0[i] = v;
  } else if (i < 560) {
    int j = i - 512;
    float v = fl ? ((const float*)b1)[j] : bs2f(((const short*)b1)[j]);
    if (!isfinite(v) || fabsf(v) > 1e4f) v = 0.f;
    Bc1[j] = v;
  }
}

// layer0 W0 (512,129,3,3) -> fp16 Wp[co][tap*160+c]: P-ch 0=x, 1..128=h0, else 0.
__global__ void prep_w0(const void* __restrict__ W0, short* __restrict__ Wp,
                        const int* __restrict__ flag) {
  int i = blockIdx.x * 256 + threadIdx.x;
  if (i >= 512 * KTOT) return;
  int fl = *flag;
  int co = i / KTOT, k = i - co * KTOT;
  int tap = k / CS, c = k - tap * CS;
  int ci = -1;
  if (c == 0) ci = 0;
  else if (c <= 128) ci = c;
  float w = 0.f;
  if (ci >= 0) {
    int widx = (co * 129 + ci) * 9 + tap;
    w = fl ? ((const float*)W0)[widx] : bs2f(((const short*)W0)[widx]);
    if (!isfinite(w) || fabsf(w) > 1e4f) w = 0.f;
  }
  Wp[i] = f2hs(w);
}

// layer1 W1 (48,140,3,3) -> fp16: P-ch 1..128=h0, 129..140=h1, else 0.
__global__ void prep_w1(const void* __restrict__ W1, short* __restrict__ Wp,
                        const int* __restrict__ flag) {
  int i = blockIdx.x * 256 + threadIdx.x;
  if (i >= 48 * KTOT) return;
  int fl = *flag;
  int co = i / KTOT, k = i - co * KTOT;
  int tap = k / CS, c = k - tap * CS;
  int ci = -1;
  if (c >= 1 && c <= 140) ci = c - 1;
  float w = 0.f;
  if (ci >= 0) {
    int widx = (co * 140 + ci) * 9 + tap;
    w = fl ? ((const float*)W1)[widx] : bs2f(((const short*)W1)[widx]);
    if (!isfinite(w) || fabsf(w) > 1e4f) w = 0.f;
  }
  Wp[i] = f2hs(w);
}

// ---- t=0 layer 0: h==0 so z = Wx*x + b (1-channel conv). Pure VALU. ----
// Block = one image row (b*64+y). Thread: hc = tid&127, px in {tid>>7 + 2k}.
__global__ __launch_bounds__(256, 4) void gate0_t0(
    const short* __restrict__ Xc, short* __restrict__ Pnext,
    const short* __restrict__ Wp, const float* __restrict__ Bc0,
    float* __restrict__ C0) {
  int rid = blockIdx.x;                        // b*64 + y
  int b = rid >> 6, y = rid & 63;
  int tid = threadIdx.x;
  __shared__ float xh[3][66];
  for (int i = tid; i < 198; i += 256) {
    int r = i / 66, px = i - r * 66;
    int yy = y - 1 + r, xx = px - 1;
    float v = 0.f;
    if ((unsigned)yy < 64u && (unsigned)xx < 64u)
      v = hs2f(Xc[b * 12 * 4096 + yy * 64 + xx]);
    xh[r][px] = v;
  }
  __syncthreads();

  int hc = tid & 127, pb = tid >> 7;           // px = pb + 2k, k<32
  float wgt[4][9];
  #pragma unroll
  for (int g = 0; g < 4; ++g)
    #pragma unroll
    for (int tap = 0; tap < 9; ++tap)
      wgt[g][tap] = hs2f(Wp[(size_t)(g * 128 + hc) * KTOT + tap * CS]);
  float bi = Bc0[hc], bff = Bc0[128 + hc], bo = Bc0[256 + hc], bg = Bc0[384 + hc];
  (void)bff;                                   // f-gate multiplies c_prev == 0
  int rowPix = (b * 64 + y) * 64;
  for (int k = 0; k < 32; ++k) {
    int x = pb + 2 * k;
    float zi = bi, zo = bo, zg = bg;
    #pragma unroll
    for (int tap = 0; tap < 9; ++tap) {
      int dy = tap / 3, dx = tap - dy * 3;
      float xv = xh[dy][x + dx];
      zi += wgt[0][tap] * xv;
      zo += wgt[2][tap] * xv;
      zg += wgt[3][tap] * xv;
    }
    float cn = sigf(zi) * tanhf(zg);
    float hn = sigf(zo) * tanhf(cn);
    int pix = rowPix + x;
    C0[(size_t)pix * 128 + hc] = cn;
    Pnext[(size_t)pix * CS + 1 + hc] = f2hs(hn);
  }
  if (tid < 64)
    Pnext[(size_t)(rowPix + tid) * CS] = Xc[(b * 12 + 1) * 4096 + y * 64 + tid];
}

// ---- layer 0 (t>=1): M=128px x N=128co. Grid = 4 nt * 512 mt. Depth-3 B ring. ----
__global__ __launch_bounds__(256, 2) void gemm_gate0(
    const short* __restrict__ Pcur, short* __restrict__ Pnext,
    const short* __restrict__ Wp, const float* __restrict__ Bc0,
    float* __restrict__ C0, const short* __restrict__ Xc,
    const short* __restrict__ zp, int t) {
  int bx = blockIdx.x;
  int nt = bx >> 9, mt = bx & 511;             // consecutive blocks share nt (weight L2 reuse)
  int b = mt >> 5, y0 = (mt & 31) * 2;
  int tid = threadIdx.x, wave = tid >> 6, lane = tid & 63;
  int ln15 = lane & 15, quad = lane >> 4;
  int wm = wave & 1, wn = wave >> 1;
  int hc = nt * 32 + wn * 16 + ln15;

  __shared__ __align__(16) short halo[2 * 4 * 66 * 32];   // dbuf, 33792 B

  float4v acc[4][4];
  #pragma unroll
  for (int i = 0; i < 4; ++i)
    #pragma unroll
    for (int j = 0; j < 4; ++j) acc[i][j] = (float4v){0.f, 0.f, 0.f, 0.f};

  // B frag addr (g, tap, c0): wbase + g*128*KTOT + tap*CS + c0
  const short* wbase = Wp + (size_t)hc * KTOT + quad * 8;
  // depth-3 ring: slot p holds tap f with f%3==p; preload (ch0, taps 0,1,2)
  short8 bb[3][4];
  #pragma unroll
  for (int p = 0; p < 3; ++p)
    #pragma unroll
    for (int g = 0; g < 4; ++g)
      bb[p][g] = *(const short8*)(wbase + (size_t)g * 128 * KTOT + p * CS);

  int yy = y0 - 1 + wave;
  bool rowOK = (yy >= 0) && (yy < 64);
  const short* rowBase = Pcur + (size_t)((b * 64 + yy) * 64) * CS;

  stage_row(rowBase, rowOK, halo + wave * 2112, lane, zp);
  __syncthreads();

  for (int ch = 0; ch < 5; ++ch) {
    const short* cur = halo + (ch & 1) * 8448;
    if (ch < 4)
      stage_row(rowBase + ch * 32 + 32, rowOK, halo + ((ch + 1) & 1) * 8448 + wave * 2112,
                lane, zp);
    #pragma unroll
    for (int tap = 0; tap < 9; ++tap) {
      int dy = tap / 3, dx = tap - dy * 3;
      const int p = tap % 3;                   // compile-time per unrolled tap

      short8 af[4];
      #pragma unroll
      for (int mf = 0; mf < 4; ++mf)
        af[mf] = *(const short8*)&cur[((wm + dy) * 66 + mf * 16 + ln15 + dx) * 32 + quad * 8];
      #pragma unroll
      for (int g = 0; g < 4; ++g)
        #pragma unroll
        for (int mf = 0; mf < 4; ++mf)
          acc[mf][g] = __builtin_amdgcn_mfma_f32_16x16x32_f16(af[mf], bb[p][g], acc[mf][g], 0, 0, 0);

      // refill slot p with tap+3 (crosses chunk boundary; clamped at the end)
      int ntap = (tap < 6) ? tap + 3 : tap - 6;
      int nch = (tap < 6) ? ch : ((ch < 4) ? ch + 1 : ch);
      int nc0 = nch * 32;
      #pragma unroll
      for (int g = 0; g < 4; ++g)
        bb[p][g] = *(const short8*)(wbase + (size_t)g * 128 * KTOT + ntap * CS + nc0);
    }
    __syncthreads();
  }

  // epilogue: all 4 gates in-register per (pix,hc)
  float bi = Bc0[hc], bff = Bc0[128 + hc], bo = Bc0[256 + hc], bg = Bc0[384 + hc];
  int rowPix = (b * 64 + y0 + wm) * 64;
  #pragma unroll
  for (int mf = 0; mf < 4; ++mf) {
    #pragma unroll
    for (int r = 0; r < 4; ++r) {
      int x = mf * 16 + quad * 4 + r;          // C/D row = quad*4 + reg
      int pix = rowPix + x;
      float zi = acc[mf][0][r] + bi;
      float zf = acc[mf][1][r] + bff;
      float zo = acc[mf][2][r] + bo;
      float zg = acc[mf][3][r] + bg;
      float cprev = C0[(size_t)pix * 128 + hc];
      float cn = sigf(zf) * cprev + sigf(zi) * tanhf(zg);
      float hn = sigf(zo) * tanhf(cn);
      C0[(size_t)pix * 128 + hc] = cn;
      Pnext[(size_t)pix * CS + 1 + hc] = f2hs(hn);
    }
  }
  if (nt == 0 && t < 11 && tid < 128) {
    int rr = tid >> 6, x = tid & 63;
    int yw = y0 + rr;
    Pnext[(size_t)((b * 64 + yw) * 64 + x) * CS] = Xc[(b * 12 + t + 1) * 4096 + yw * 64 + x];
  }
}

// ---- layer 1 (R11 verbatim): M=128px x N=48co. Grid 512. ----
__global__ __launch_bounds__(256, 2) void gemm_gate1(
    const short* __restrict__ Prd, short* __restrict__ Pwr,
    const short* __restrict__ Wp, const float* __restrict__ Bc1,
    float* __restrict__ C1, void* __restrict__ outp,
    const short* __restrict__ zp, const int* __restrict__ flagp, int t) {
  int bid = blockIdx.x;                        // 0..511
  int b = bid >> 5, y0 = (bid & 31) * 2;
  int tid = threadIdx.x, wave = tid >> 6, lane = tid & 63;
  int ln15 = lane & 15, quad = lane >> 4;
  int wr = wave >> 1, wh = wave & 1;
  int flagv = *flagp;

  __shared__ __align__(16) short halo[2 * 4 * 66 * 32];   // 33792 B

  float4v acc[2][3];
  #pragma unroll
  for (int i = 0; i < 2; ++i)
    #pragma unroll
    for (int j = 0; j < 3; ++j) acc[i][j] = (float4v){0.f, 0.f, 0.f, 0.f};

  int yy = y0 - 1 + wave;
  bool rowOK = (yy >= 0) && (yy < 64);
  const short* rowBase = Prd + (size_t)((b * 64 + yy) * 64) * CS;

  const short* wbase = Wp + (size_t)ln15 * KTOT + quad * 8;
  short8 bcur[3], bnxt[3];
  #pragma unroll
  for (int nf = 0; nf < 3; ++nf)
    bcur[nf] = *(const short8*)(wbase + (size_t)nf * 16 * KTOT);

  stage_row(rowBase, rowOK, halo + wave * 2112, lane, zp);
  __syncthreads();

  for (int ch = 0; ch < 5; ++ch) {
    int c0 = ch * 32;
    const short* cur = halo + (ch & 1) * 8448;
    if (ch < 4)
      stage_row(rowBase + c0 + 32, rowOK, halo + ((ch + 1) & 1) * 8448 + wave * 2112,
                lane, zp);
    #pragma unroll
    for (int tap = 0; tap < 9; ++tap) {
      int dy = tap / 3, dx = tap - dy * 3;
      int ntap = (tap < 8) ? tap + 1 : 0;
      int nc0 = (tap < 8) ? c0 : ((ch < 4) ? c0 + 32 : c0);
      #pragma unroll
      for (int nf = 0; nf < 3; ++nf)
        bnxt[nf] = *(const short8*)(wbase + (size_t)nf * 16 * KTOT + ntap * CS + nc0);

      short8 af[2];
      #pragma unroll
      for (int mf = 0; mf < 2; ++mf)
        af[mf] = *(const short8*)&cur[((wr + dy) * 66 + wh * 32 + mf * 16 + ln15 + dx) * 32
                                      + quad * 8];
      #pragma unroll
      for (int nf = 0; nf < 3; ++nf)
        #pragma unroll
        for (int mf = 0; mf < 2; ++mf)
          acc[mf][nf] = __builtin_amdgcn_mfma_f32_16x16x32_f16(af[mf], bcur[nf], acc[mf][nf], 0, 0, 0);
      #pragma unroll
      for (int nf = 0; nf < 3; ++nf) bcur[nf] = bnxt[nf];
    }
    __syncthreads();
  }

  // z -> LDS (reuse halo: 128*48 fp32 = 24576 B), then gate pass
  float* zbuf = (float*)halo;
  #pragma unroll
  for (int mf = 0; mf < 2; ++mf)
    #pragma unroll
    for (int nf = 0; nf < 3; ++nf)
      #pragma unroll
      for (int r = 0; r < 4; ++r) {
        int pxl = wr * 64 + wh * 32 + mf * 16 + quad * 4 + r;
        zbuf[pxl * 48 + nf * 16 + ln15] = acc[mf][nf][r];
      }
  __syncthreads();

  #pragma unroll
  for (int k = 0; k < 6; ++k) {
    int id = k * 256 + tid;
    int hc = id >> 7, pxl = id & 127;
    float zi = zbuf[pxl * 48 + hc]      + Bc1[hc];
    float zf = zbuf[pxl * 48 + 12 + hc] + Bc1[12 + hc];
    float zo = zbuf[pxl * 48 + 24 + hc] + Bc1[24 + hc];
    float zg = zbuf[pxl * 48 + 36 + hc] + Bc1[36 + hc];
    int y = y0 + (pxl >> 6), x = pxl & 63;
    int pix = (b * 64 + y) * 64 + x;
    float cprev = C1[(size_t)pix * 12 + hc];
    float cn = sigf(zf) * cprev + sigf(zi) * tanhf(zg);
    float hn = sigf(zo) * tanhf(cn);
    C1[(size_t)pix * 12 + hc] = cn;
    Pwr[(size_t)pix * CS + 129 + hc] = f2hs(hn);
    if (t == 11) {
      int oidx = (b * 12 + hc) * 4096 + y * 64 + x;
      if (flagv) ((float*)outp)[oidx] = hn;
      else ((short*)outp)[oidx] = f2bs(hn);
    }
  }
}

extern "C" void kernel_launch(void* const* d_in, const int* in_sizes, int n_in,
                              void* d_out, int out_size, void* d_ws, size_t ws_size,
                              hipStream_t stream) {
  const void* hist = d_in[0];                  // (16,12,4096,1)
  const void* W0 = d_in[2];                    // (512,129,3,3)
  const void* b0 = d_in[3];
  const void* W1 = d_in[4];                    // (48,140,3,3)
  const void* b1 = d_in[5];

  char* ws = (char*)d_ws;
  const size_t PszB = (size_t)16 * 4096 * CS * 2;     // 20,971,520
  short* P[2] = {(short*)ws, (short*)(ws + PszB)};
  float* C0 = (float*)(ws + 2 * PszB);                // 33,554,432
  const size_t C0e = 2 * PszB + 33554432;
  float* C1 = (float*)(ws + C0e);                     // 3,145,728
  const size_t C1e = C0e + 3145728;
  short* zp = (short*)(ws + C1e);                     // 256 B zero page
  const size_t zpe = C1e + 256;
  short* Xc = (short*)(ws + zpe);                     // 1,572,864
  const size_t Xce = zpe + 1572864;
  short* Wp0 = (short*)(ws + Xce);                    // 1,474,560
  const size_t W0e = Xce + (size_t)512 * KTOT * 2;
  short* Wp1 = (short*)(ws + W0e);                    // 138,240
  const size_t W1e = W0e + (size_t)48 * KTOT * 2;
  float* Bc0 = (float*)(ws + W1e);                    // 2048
  float* Bc1 = (float*)(ws + W1e + 2048);             // 192
  int* flag = (int*)(ws + W1e + 2048 + 192);          // total ~82 MiB

  hipMemsetAsync(ws, 0, zpe, stream);                 // P pair + C0 + C1 + zero page
  detect_dtype<<<1, 64, 0, stream>>>((const unsigned short*)W0, flag);
  canon_x<<<3072, 256, 0, stream>>>(hist, Xc, flag);
  canon_b<<<3, 256, 0, stream>>>(b0, b1, Bc0, Bc1, flag);
  prep_w0<<<(512 * KTOT + 255) / 256, 256, 0, stream>>>(W0, Wp0, flag);
  prep_w1<<<(48 * KTOT + 255) / 256, 256, 0, stream>>>(W1, Wp1, flag);

  // t = 0: h==0 -> specialized 1-channel conv for layer0
  gate0_t0<<<1024, 256, 0, stream>>>(Xc, P[1], Wp0, Bc0, C0);
  gemm_gate1<<<512, 256, 0, stream>>>(P[1], P[0], Wp1, Bc1, C1, d_out, zp, flag, 0);

  for (int t = 1; t < 12; ++t) {
    gemm_gate0<<<2048, 256, 0, stream>>>(P[t & 1], P[(t + 1) & 1], Wp0, Bc0, C0, Xc, zp, t);
    gemm_gate1<<<512, 256, 0, stream>>>(P[(t + 1) & 1], P[t & 1], Wp1, Bc1, C1,
                                        d_out, zp, flag, t);
  }
}